// Round 18
// baseline (945.034 us; speedup 1.0000x reference)
//
#include <hip/hip_runtime.h>
#include <hip/hip_bf16.h>
#include <math.h>

#define BATCH 2
#define SEQL 8192
#define DD 256
#define HDIM 1024
#define NLAYER 6
#define WSZ 512
#define NVOCAB 32
#define NTOK (BATCH*SEQL)
#define PLN (DD*HDIM)   // 262144 elems per weight plane

typedef unsigned short u16;
typedef __attribute__((ext_vector_type(8))) short bf16x8;
typedef __attribute__((ext_vector_type(4))) float f32x4;

union B8 { uint4 u; bf16x8 b; ushort s[8]; uint w[4]; };

__device__ inline float bf2f(u16 v){
  unsigned int u = ((unsigned int)v) << 16;
  return __uint_as_float(u);
}
__device__ inline u16 f2bf(float f){
  unsigned int u = __float_as_uint(f);
  u += 0x7fff + ((u >> 16) & 1);   // RNE
  return (u16)(u >> 16);
}

__device__ __forceinline__ void gload16(const void* g, void* l){
  __builtin_amdgcn_global_load_lds(
      (const __attribute__((address_space(1))) unsigned int*)g,
      (__attribute__((address_space(3))) unsigned int*)l, 16, 0, 0);
}

// ---------------- one-time rope tables (fp32) ----------------
__global__ void k_tables(float* __restrict__ ct, float* __restrict__ st){
  int idx = blockIdx.x * 256 + threadIdx.x;     // t*128 + i
  if (idx >= SEQL * 128) return;
  int t = idx >> 7, i = idx & 127;
  float freq = expf(-((float)i / 128.0f) * 9.210340371976184f);  // ln(10000)
  float fr = (float)t * freq;
  ct[idx] = cosf(fr);
  st[idx] = sinf(fr);
}

// ---------------- embedding gather (fp32 table), XCD-chunked ----------------
__global__ void k_embed(const int* __restrict__ tokens, const float* __restrict__ emb,
                        float* __restrict__ x){
  int vbid = (blockIdx.x & 7) * 512 + (blockIdx.x >> 3);   // 4096 blocks
  int idx = vbid * 256 + threadIdx.x;           // bt*64 + dvec
  int bt = idx >> 6, dv = (idx & 63) << 2;
  int tok = tokens[bt];
  *(float4*)(x + bt * DD + dv) = *(const float4*)(emb + tok * DD + dv);
}

// ------- rope: x(fp32) -> qk (roped bf16, row-major) + xvT (bf16 transposed) --
// 256 blocks x 256 thr; block = 64 tokens (XCD-chunked). LDS tile transpose.
__global__ void __launch_bounds__(256) k_rope2(const float* __restrict__ x,
                                               const float* __restrict__ ct,
                                               const float* __restrict__ st,
                                               u16* __restrict__ qk,
                                               u16* __restrict__ xvT){
  __shared__ u16 vt[256][66];     // [dim][token-in-block], pad -> conflict-free
  const int tid = threadIdx.x;
  const int vbid = (blockIdx.x & 7) * 32 + (blockIdx.x >> 3);  // match attn map
  const int tok0 = vbid * 64;

  #pragma unroll
  for (int u = 0; u < 32; ++u){
    int e = u*256 + tid;          // 0..8191 = tok*128 + i
    int tok = e >> 7, i = e & 127;
    int row = tok0 + tok;
    int t = row & (SEQL - 1);
    float x1 = x[(size_t)row*DD + i];
    float x2 = x[(size_t)row*DD + 128 + i];
    float c = ct[t*128 + i], s = st[t*128 + i];
    qk[(size_t)row*DD + i]       = f2bf(x1*c - x2*s);
    qk[(size_t)row*DD + 128 + i] = f2bf(x2*c + x1*s);
    vt[i][tok]       = f2bf(x1);
    vt[i + 128][tok] = f2bf(x2);
  }
  __syncthreads();

  const int batch = tok0 >> 13;
  const int tloc = tok0 & (SEQL - 1);
  #pragma unroll
  for (int u = 0; u < 8; ++u){
    int j = u*256 + tid;          // 0..2047 = dim*8 + tg
    int dim = j >> 3, tg = j & 7;
    B8 pk;
    #pragma unroll
    for (int e = 0; e < 8; ++e) pk.s[e] = vt[dim][tg*8 + e];
    *(uint4*)(xvT + ((size_t)batch*DD + dim)*SEQL + tloc + tg*8) = pk.u;
  }
}

// ---------------- MFMA sliding-window attention + fused LN ----------------
// 256 blocks x 512 threads (8 waves). Block: 64 queries, full key window.
// K: double-buffered LDS (2x32KB), one barrier per tile. V: direct per-wave
// fragment loads from xvT (L2-resident, R7-verified pattern) -> LDS 68KB
// -> 2 blocks/CU co-resident. Epilogue: 2 barriers, Obuf combine, fused LN.
__global__ void __launch_bounds__(512, 2) k_attn2(const u16* __restrict__ qk,
                                                  const u16* __restrict__ xvT,
                                                  const float* __restrict__ x,
                                                  float* __restrict__ y,
                                                  const float* __restrict__ g,
                                                  const float* __restrict__ b,
                                                  u16* __restrict__ lnx,
                                                  int fuse){
  __shared__ char smem[68096];    // max(2x32KB K dbuf, 67.6KB Obuf + redl)

  const int tid = threadIdx.x;
  const int lane = tid & 63;
  const int w = tid >> 6;
  const int qh = w >> 1, kh = w & 1;    // qh 0..3
  const int l15 = lane & 15, lg = lane >> 4;

  // XCD-aware chunked swizzle: 256 blocks, 8 XCDs, 32 blocks each (bijective)
  const int qg = (blockIdx.x & 7) * 32 + (blockIdx.x >> 3);
  const int qb = qg * 64;
  const int t0 = qb & (SEQL - 1);
  const int batch = qb >> 13;
  const size_t bbase = (size_t)batch << 13;

  // ---- preload Q B-frags (16 queries of this wave) ----
  uint4 qf[8];
  {
    const u16* qr = qk + (size_t)(qb + qh*16 + l15) * DD + lg*4;
    #pragma unroll
    for (int s = 0; s < 8; ++s){
      uint2 a = *(const uint2*)(qr + s*32);
      uint2 bq = *(const uint2*)(qr + s*32 + 16);
      qf[s] = make_uint4(a.x, a.y, bq.x, bq.y);
    }
  }

  f32x4 oacc[16];
  #pragma unroll
  for (int d = 0; d < 16; ++d) oacc[d] = (f32x4){0.f, 0.f, 0.f, 0.f};
  float lacc = 0.f;

  const int p0 = (t0 >= WSZ) ? (t0 - WSZ) : 0;
  const int ntile = ((t0 - p0) >> 6) + 1;

  const int sk15 = tid & 15, skt = (tid >> 4) & 3, sc = tid >> 6;   // K stage

  uint4 kreg[4];

  // ---- load + write K tile 0 to buffer 0 ----
  {
    const u16* sb = qk + (bbase + (size_t)p0 + skt*16 + sk15) * DD;
    #pragma unroll
    for (int u = 0; u < 4; ++u) kreg[u] = *(const uint4*)(sb + u*64 + sc*8);
  }
  #pragma unroll
  for (int u = 0; u < 4; ++u){
    int d0 = u*64 + sc*8;
    int s = d0 >> 5, r = d0 & 31;
    int h = r >> 4, lgw = (r & 15) >> 2;
    int rec = ((s*4 + skt)*4 + lgw)*16 + sk15;
    char* wp = smem + rec*16 + h*8;
    *(uint2*)wp         = make_uint2(kreg[u].x, kreg[u].y);
    *(uint2*)(wp + 256) = make_uint2(kreg[u].z, kreg[u].w);
  }
  __syncthreads();

  int cur = 0;
  for (int ti = 0; ti < ntile; ++ti){
    const int p = p0 + ti*64;
    // issue next K tile's global loads (drain under compute)
    if (ti + 1 < ntile){
      const u16* sb = qk + (bbase + (size_t)(p + 64) + skt*16 + sk15) * DD;
      #pragma unroll
      for (int u = 0; u < 4; ++u) kreg[u] = *(const uint4*)(sb + u*64 + sc*8);
    }

    char* Klds = smem + cur*32768;

    // --- S^T = K · Q^T ---
    f32x4 sacc[2];
    sacc[0] = (f32x4){0.f,0.f,0.f,0.f};
    sacc[1] = (f32x4){0.f,0.f,0.f,0.f};
    #pragma unroll
    for (int s = 0; s < 8; ++s){
      B8 ka0, ka1, qbf;
      ka0.b = *(const bf16x8*)(Klds + (((s*4 + kh*2+0)*4 + lg)*16 + l15)*16);
      ka1.b = *(const bf16x8*)(Klds + (((s*4 + kh*2+1)*4 + lg)*16 + l15)*16);
      qbf.u = qf[s];
      sacc[0] = __builtin_amdgcn_mfma_f32_16x16x32_bf16(ka0.b, qbf.b, sacc[0], 0, 0, 0);
      sacc[1] = __builtin_amdgcn_mfma_f32_16x16x32_bf16(ka1.b, qbf.b, sacc[1], 0, 0, 0);
    }

    // --- mask + exp + pack P^T -> PV A-frag ---
    B8 pa;
    #pragma unroll
    for (int ktp = 0; ktp < 2; ++ktp){
      int kbase = p + kh*32 + ktp*16 + lg*4;
      int qpos = t0 + qh*16 + l15;
      #pragma unroll
      for (int r = 0; r < 4; ++r){
        int kpos = kbase + r;
        float sv = sacc[ktp][r] * 0.0625f;
        bool ok = (kpos <= qpos) && (qpos <= kpos + WSZ);
        float pv = ok ? __expf(sv) : 0.0f;
        lacc += pv;
        pa.s[ktp*4 + r] = f2bf(pv);
      }
    }

    // --- O += P · V : V^T fragments direct from global (L2-resident) ---
    #pragma unroll
    for (int dimt = 0; dimt < 16; ++dimt){
      const u16* vr = xvT + ((size_t)(batch*DD + dimt*16 + l15))*SEQL
                          + p + kh*32 + lg*4;
      uint2 a = *(const uint2*)vr;
      uint2 bq = *(const uint2*)(vr + 16);
      B8 vb; vb.u = make_uint4(a.x, a.y, bq.x, bq.y);
      oacc[dimt] = __builtin_amdgcn_mfma_f32_16x16x32_bf16(pa.b, vb.b, oacc[dimt], 0, 0, 0);
    }

    // --- write prefetched K tile into the OTHER buffer ---
    if (ti + 1 < ntile){
      char* nK = smem + (cur ^ 1)*32768;
      #pragma unroll
      for (int u = 0; u < 4; ++u){
        int d0 = u*64 + sc*8;
        int s = d0 >> 5, r = d0 & 31;
        int h = r >> 4, lgw = (r & 15) >> 2;
        int rec = ((s*4 + skt)*4 + lgw)*16 + sk15;
        char* wp = nK + rec*16 + h*8;
        *(uint2*)wp         = make_uint2(kreg[u].x, kreg[u].y);
        *(uint2*)(wp + 256) = make_uint2(kreg[u].z, kreg[u].w);
      }
    }
    __syncthreads();          // ONE barrier per tile
    cur ^= 1;
  }

  // ---- epilogue: 2 barriers, full-LDS combine, fused LN ----
  float* Obuf = (float*)smem;                 // [64][264] fp32 = 67.6 KB
  float* redl = (float*)(smem + 67584);       // 128 floats

  const int q = tid >> 3, dv = (tid & 7) * 4;
  float4 xrs[8];
  #pragma unroll
  for (int pass = 0; pass < 8; ++pass)
    xrs[pass] = *(const float4*)(x + (size_t)(qb + q)*DD + pass*32 + dv);

  lacc += __shfl_xor(lacc, 16, 64);
  lacc += __shfl_xor(lacc, 32, 64);
  if (lane < 16) redl[kh*64 + qh*16 + l15] = lacc;
  if (kh == 0){
    #pragma unroll
    for (int dimt = 0; dimt < 16; ++dimt)
      #pragma unroll
      for (int r = 0; r < 4; ++r)
        Obuf[(qh*16 + lg*4 + r)*264 + dimt*16 + l15] = oacc[dimt][r];
  }
  __syncthreads();
  if (kh == 1){
    #pragma unroll
    for (int dimt = 0; dimt < 16; ++dimt)
      #pragma unroll
      for (int r = 0; r < 4; ++r)
        Obuf[(qh*16 + lg*4 + r)*264 + dimt*16 + l15] += oacc[dimt][r];
  }
  __syncthreads();

  float inv = 1.0f / (redl[q] + redl[64 + q]);
  float4 ovs[8];
  float lsum = 0.f, lss = 0.f;
  #pragma unroll
  for (int pass = 0; pass < 8; ++pass){
    float4 o = *(float4*)&Obuf[q*264 + pass*32 + dv];
    float4 ov;
    ov.x = xrs[pass].x + o.x * inv;
    ov.y = xrs[pass].y + o.y * inv;
    ov.z = xrs[pass].z + o.z * inv;
    ov.w = xrs[pass].w + o.w * inv;
    *(float4*)(y + (size_t)(qb + q)*DD + pass*32 + dv) = ov;
    ovs[pass] = ov;
    lsum += ov.x + ov.y + ov.z + ov.w;
    lss  += ov.x*ov.x + ov.y*ov.y + ov.z*ov.z + ov.w*ov.w;
  }

  if (fuse){
    #pragma unroll
    for (int o = 1; o < 8; o <<= 1){
      lsum += __shfl_xor(lsum, o, 64);
      lss  += __shfl_xor(lss,  o, 64);
    }
    float m = lsum * (1.0f / DD);
    float var = lss * (1.0f / DD) - m * m;
    float rs = rsqrtf(var + 1e-5f);
    #pragma unroll
    for (int pass = 0; pass < 8; ++pass){
      float4 gf = *(const float4*)(g + pass*32 + dv);
      float4 bf = *(const float4*)(b + pass*32 + dv);
      ushort4 o4;
      o4.x = f2bf((ovs[pass].x - m) * rs * gf.x + bf.x);
      o4.y = f2bf((ovs[pass].y - m) * rs * gf.y + bf.y);
      o4.z = f2bf((ovs[pass].z - m) * rs * gf.z + bf.z);
      o4.w = f2bf((ovs[pass].w - m) * rs * gf.w + bf.w);
      *(ushort4*)(lnx + (size_t)(qb + q) * DD + pass*32 + dv) = o4;
    }
  }
}

// ---------------- layernorm (fallback when ws too small) ----------------
__global__ void __launch_bounds__(256) k_ln(const float* __restrict__ in,
                                            const float* __restrict__ g,
                                            const float* __restrict__ b,
                                            u16* __restrict__ out){
  int wid = (blockIdx.x * 256 + threadIdx.x) >> 6;
  int lane = threadIdx.x & 63;
  float4 v = *(const float4*)(in + wid * DD + lane * 4);
  float s = v.x + v.y + v.z + v.w;
  float ss = v.x * v.x + v.y * v.y + v.z * v.z + v.w * v.w;
  #pragma unroll
  for (int o = 32; o; o >>= 1){ s += __shfl_xor(s, o, 64); ss += __shfl_xor(ss, o, 64); }
  float m = s * (1.0f / DD);
  float var = ss * (1.0f / DD) - m * m;
  float rs = rsqrtf(var + 1e-5f);
  float4 gf = *(const float4*)(g + lane * 4);
  float4 bf = *(const float4*)(b + lane * 4);
  ushort4 o4;
  o4.x = f2bf((v.x - m) * rs * gf.x + bf.x);
  o4.y = f2bf((v.y - m) * rs * gf.y + bf.y);
  o4.z = f2bf((v.z - m) * rs * gf.z + bf.z);
  o4.w = f2bf((v.w - m) * rs * gf.w + bf.w);
  *(ushort4*)(out + wid * DD + lane * 4) = o4;
}

// -------- weight split: fp32 W[K][N] -> frag-major bf16 planes ----------
template<int KDIM, int NDIM>
__device__ __forceinline__ void split_one(const float* __restrict__ W,
                                          u16* __restrict__ Phi, int idx){
  int c15 = idx & 15;
  int lg = (idx >> 4) & 3;
  int nt = (idx >> 6) % (NDIM/16);
  int ks = idx / ((NDIM/16) * 64);
  int col = nt*16 + c15;
  B8 hi;
  #pragma unroll
  for (int j = 0; j < 8; ++j){
    int k = ks*32 + (j >> 2)*16 + lg*4 + (j & 3);
    hi.s[j] = f2bf(W[(size_t)k * NDIM + col]);
  }
  *(uint4*)(Phi + (size_t)idx * 8) = hi.u;
}

// all 6 layers at once: grid 1536
__global__ void __launch_bounds__(256) k_splitall(const float* __restrict__ w1,
                                                  const float* __restrict__ w2,
                                                  u16* __restrict__ P){
  int bk = blockIdx.x;              // 0..1535
  int L = bk >> 8, r = bk & 255;
  u16* PL = P + (size_t)L * 2 * PLN;
  if (r < 128) split_one<DD, HDIM>(w1 + (size_t)L*PLN, PL, r*256 + threadIdx.x);
  else         split_one<HDIM, DD>(w2 + (size_t)L*PLN, PL + PLN, (r-128)*256 + threadIdx.x);
}

// ---------------- MFMA GEMM: C = A(bf16) @ W(bf16 frag-major plane) ----------
// BM=128, BN=64, BK=64. 4 waves (2x2), 64x32 per wave. B via global_load_lds.
// XCD-pinned block mapping: m-tile -> XCD m/16 (aligned with attn token map).
// EPI 0: bias+GELU -> bf16 h. EPI 1: bias + residual -> fp32 x.
template<int KDIM, int NDIM, int EPI>
__global__ void __launch_bounds__(256, 4) k_gemm(const u16* __restrict__ A,
                                              const u16* __restrict__ BhG,
                                              const float* __restrict__ bias,
                                              const float* __restrict__ res,
                                              float* __restrict__ outf,
                                              u16* __restrict__ outh){
  __shared__ char smem[18432 + 8192];
  char* As = smem;                            // [128][144B] padded row-major
  char* Bs = smem + 18432;                    // 8 KB: [chunk][rec]

  const int tid = threadIdx.x;
  const int lane = tid & 63;
  const int w = tid >> 6;
  const int wr = w >> 1, wc = w & 1;
  const int l15 = lane & 15, lg = lane >> 4;
  const int lin = blockIdx.x;
  const int xcd = lin & 7;
  const int idx = lin >> 3;
  const int m0 = (xcd * 16 + (idx & 15)) * 128;
  const int n0 = (idx >> 4) * 64;
  const int NT16 = NDIM / 16;

  f32x4 acc[4][2];
  #pragma unroll
  for (int a = 0; a < 4; ++a){
    acc[a][0] = (f32x4){0.f,0.f,0.f,0.f};
    acc[a][1] = (f32x4){0.f,0.f,0.f,0.f};
  }

  for (int kb = 0; kb < KDIM/64; ++kb){
    __syncthreads();
    #pragma unroll
    for (int p = 0; p < 4; ++p){
      int c = p*256 + tid;
      int row = c >> 3, cc = c & 7;
      uint4 v = *(const uint4*)(A + (size_t)(m0 + row) * KDIM + kb*64 + cc*8);
      *(uint4*)(As + row*144 + cc*16) = v;
    }
    #pragma unroll
    for (int p = 0; p < 2; ++p){
      int j = p*256 + tid;                       // 0..511
      int chunk = j >> 6, r = j & 63;            // chunk = s*4 + ntl
      const u16* src = BhG
          + (((size_t)(kb*2 + (chunk >> 2)) * NT16 + (n0 >> 4) + (chunk & 3))*64 + r)*8;
      gload16(src, Bs + j*16);
    }
    __syncthreads();

    #pragma unroll
    for (int s = 0; s < 2; ++s){
      B8 af[4], bhf[2];
      #pragma unroll
      for (int a = 0; a < 4; ++a){
        const char* ab = As + (wr*64 + a*16 + l15)*144 + s*64 + lg*8;
        uint2 lo = *(const uint2*)ab;
        uint2 hi = *(const uint2*)(ab + 32);
        af[a].u = make_uint4(lo.x, lo.y, hi.x, hi.y);
      }
      #pragma unroll
      for (int c = 0; c < 2; ++c){
        int off = (((s*4 + wc*2 + c)*64) + lg*16 + l15)*16;
        bhf[c].u = *(const uint4*)(Bs + off);
      }
      #pragma unroll
      for (int a = 0; a < 4; ++a)
        #pragma unroll
        for (int c = 0; c < 2; ++c)
          acc[a][c] = __builtin_amdgcn_mfma_f32_16x16x32_bf16(af[a].b, bhf[c].b, acc[a][c], 0, 0, 0);
    }
  }

  float bv[2];
  bv[0] = bias[n0 + wc*32 + l15];
  bv[1] = bias[n0 + wc*32 + 16 + l15];

  #pragma unroll
  for (int a = 0; a < 4; ++a){
    #pragma unroll
    for (int c = 0; c < 2; ++c){
      #pragma unroll
      for (int r = 0; r < 4; ++r){
        int row = m0 + wr*64 + a*16 + lg*4 + r;
        int col = n0 + wc*32 + c*16 + l15;
        float v = acc[a][c][r] + bv[c];
        if (EPI == 0){
          float gl = 0.5f * v * (1.0f + erff(v * 0.70710678f));
          outh[(size_t)row * NDIM + col] = f2bf(gl);
        } else {
          outf[(size_t)row * NDIM + col] = v + res[(size_t)row * NDIM + col];
        }
      }
    }
  }
}

// ---------------- final LN + (256x32) projection, fp32 out, XCD-chunked ------
__global__ void __launch_bounds__(256) k_final(const float* __restrict__ x,
                                               const float* __restrict__ g,
                                               const float* __restrict__ b,
                                               const float* __restrict__ wout,
                                               const float* __restrict__ bout,
                                               float* __restrict__ out){
  __shared__ float lds[4][256];
  int vbid = (blockIdx.x & 7) * 512 + (blockIdx.x >> 3);   // 4096 blocks
  int widx = threadIdx.x >> 6, lane = threadIdx.x & 63;
  int bt = vbid * 4 + widx;
  float4 v = *(const float4*)(x + bt * DD + lane * 4);
  float s = v.x + v.y + v.z + v.w;
  float ss = v.x * v.x + v.y * v.y + v.z * v.z + v.w * v.w;
  #pragma unroll
  for (int o = 32; o; o >>= 1){ s += __shfl_xor(s, o, 64); ss += __shfl_xor(ss, o, 64); }
  float m = s * (1.0f / DD);
  float var = ss * (1.0f / DD) - m * m;
  float rs = rsqrtf(var + 1e-5f);
  float4 gf = *(const float4*)(g + lane * 4);
  float4 bf = *(const float4*)(b + lane * 4);
  lds[widx][lane * 4 + 0] = (v.x - m) * rs * gf.x + bf.x;
  lds[widx][lane * 4 + 1] = (v.y - m) * rs * gf.y + bf.y;
  lds[widx][lane * 4 + 2] = (v.z - m) * rs * gf.z + bf.z;
  lds[widx][lane * 4 + 3] = (v.w - m) * rs * gf.w + bf.w;
  __syncthreads();
  int vo = lane & 31, half = lane >> 5;
  const float* lp = &lds[widx][half * 128];
  const float* wp = wout + half * 128 * NVOCAB + vo;
  float acc = 0;
  #pragma unroll 4
  for (int d = 0; d < 128; ++d) acc += lp[d] * wp[d * NVOCAB];
  acc += __shfl_down(acc, 32, 64);
  if (lane < 32) out[bt * NVOCAB + vo] = acc + bout[vo];
}

extern "C" void kernel_launch(void* const* d_in, const int* in_sizes, int n_in,
                              void* d_out, int out_size, void* d_ws, size_t ws_size,
                              hipStream_t stream) {
  const int*   tokens = (const int*)d_in[0];
  const float* emb   = (const float*)d_in[1];
  const float* ffs   = (const float*)d_in[2];
  const float* ffb   = (const float*)d_in[3];
  const float* w1    = (const float*)d_in[4];
  const float* b1    = (const float*)d_in[5];
  const float* w2    = (const float*)d_in[6];
  const float* b2    = (const float*)d_in[7];
  const float* lnfs  = (const float*)d_in[8];
  const float* lnfb  = (const float*)d_in[9];
  const float* wout  = (const float*)d_in[10];
  const float* bout  = (const float*)d_in[11];
  float* out = (float*)d_out;

  char* ws = (char*)d_ws;
  float* x    = (float*)(ws);                         // 16 MB fp32
  float* y    = (float*)(ws + (size_t)16*1024*1024);  // 16 MB fp32
  u16*   buf8 = (u16*)  (ws + (size_t)32*1024*1024);  //  8 MB bf16 (xvT)
  u16*   qk   = (u16*)  (ws + (size_t)40*1024*1024);  //  8 MB bf16
  u16*   pln  = (u16*)  (ws + (size_t)48*1024*1024);  //  6 MB (12 planes)
  u16*   h    = (u16*)  (ws + (size_t)56*1024*1024);  // 32 MB bf16 (56..88)

  float* ct = (float*)(ws + (size_t)96*1024*1024);    // 96..100 (bigws)
  float* st = (float*)(ws + (size_t)100*1024*1024);   // 100..104 (bigws)
  const int bigws = (ws_size >= (size_t)104*1024*1024) ? 1 : 0;
  if (!bigws){
    ct = (float*)(ws + (size_t)48*1024*1024);          // 48..52 (pln unused then)
    st = (float*)(ws + (size_t)52*1024*1024);          // 52..56
  }
  const int fuse = (ws_size >= (size_t)96*1024*1024) ? 1 : 0;
  u16* lnx = fuse ? (u16*)(ws + (size_t)88*1024*1024) : buf8; // bf16, 8 MB

  k_tables<<<4096, 256, 0, stream>>>(ct, st);
  k_embed<<<4096, 256, 0, stream>>>(tokens, emb, x);
  if (bigws) k_splitall<<<1536, 256, 0, stream>>>(w1, w2, pln);
  for (int L = 0; L < NLAYER; ++L){
    k_rope2<<<256, 256, 0, stream>>>(x, ct, st, qk, buf8);
    k_attn2<<<256, 512, 0, stream>>>(qk, buf8, x, y,
                                     ffs + L*DD, ffb + L*DD, lnx, fuse);
    if (!fuse)
      k_ln<<<4096, 256, 0, stream>>>(y, ffs + L*DD, ffb + L*DD, lnx);
    const u16* PL;
    if (bigws){
      PL = pln + (size_t)L*2*PLN;
    } else {
      k_splitall<<<256, 256, 0, stream>>>(w1 + (size_t)L*PLN, w2 + (size_t)L*PLN, qk);
      PL = qk;
    }
    k_gemm<DD, HDIM, 0><<<2048, 256, 0, stream>>>(
        lnx, PL, b1 + L*HDIM, nullptr, nullptr, h);
    k_gemm<HDIM, DD, 1><<<512, 256, 0, stream>>>(
        h, PL + PLN, b2 + L*DD, y, x, nullptr);
  }
  k_final<<<4096, 256, 0, stream>>>(x, lnfs, lnfb, wout, bout, out);
}

// Round 19
// 675.859 us; speedup vs baseline: 1.3983x; 1.3983x over previous
//
#include <hip/hip_runtime.h>
#include <hip/hip_bf16.h>
#include <math.h>

#define BATCH 2
#define SEQL 8192
#define DD 256
#define HDIM 1024
#define NLAYER 6
#define WSZ 512
#define NVOCAB 32
#define NTOK (BATCH*SEQL)
#define PLN (DD*HDIM)   // 262144 elems per weight plane

typedef unsigned short u16;
typedef __attribute__((ext_vector_type(8))) short bf16x8;
typedef __attribute__((ext_vector_type(4))) float f32x4;

union B8 { uint4 u; bf16x8 b; ushort s[8]; uint w[4]; };

__device__ inline float bf2f(u16 v){
  unsigned int u = ((unsigned int)v) << 16;
  return __uint_as_float(u);
}
__device__ inline u16 f2bf(float f){
  unsigned int u = __float_as_uint(f);
  u += 0x7fff + ((u >> 16) & 1);   // RNE
  return (u16)(u >> 16);
}

__device__ __forceinline__ void gload16(const void* g, void* l){
  __builtin_amdgcn_global_load_lds(
      (const __attribute__((address_space(1))) unsigned int*)g,
      (__attribute__((address_space(3))) unsigned int*)l, 16, 0, 0);
}

// ---------------- one-time rope tables (fp32) ----------------
__global__ void k_tables(float* __restrict__ ct, float* __restrict__ st){
  int idx = blockIdx.x * 256 + threadIdx.x;     // t*128 + i
  if (idx >= SEQL * 128) return;
  int t = idx >> 7, i = idx & 127;
  float freq = expf(-((float)i / 128.0f) * 9.210340371976184f);  // ln(10000)
  float fr = (float)t * freq;
  ct[idx] = cosf(fr);
  st[idx] = sinf(fr);
}

// ---------------- embedding gather (fp32 table), XCD-chunked ----------------
__global__ void k_embed(const int* __restrict__ tokens, const float* __restrict__ emb,
                        float* __restrict__ x){
  int vbid = (blockIdx.x & 7) * 512 + (blockIdx.x >> 3);   // 4096 blocks
  int idx = vbid * 256 + threadIdx.x;           // bt*64 + dvec
  int bt = idx >> 6, dv = (idx & 63) << 2;
  int tok = tokens[bt];
  *(float4*)(x + bt * DD + dv) = *(const float4*)(emb + tok * DD + dv);
}

// ------- rope: x(fp32) -> qk (roped bf16) and xv (bf16 copy), XCD-chunked ----
__global__ void k_rope(const float* __restrict__ x, const float* __restrict__ ct,
                       const float* __restrict__ st, u16* __restrict__ qk,
                       u16* __restrict__ xv){
  int vbid = (blockIdx.x & 7) * 256 + (blockIdx.x >> 3);   // 2048 blocks
  int idx = vbid * 256 + threadIdx.x;           // bt*32 + ivec  (half-dim /4)
  int bt = idx >> 5, iv = (idx & 31) << 2;
  int t = bt & (SEQL - 1);
  const float* xr = x + bt * DD;
  float4 x1 = *(const float4*)(xr + iv);
  float4 x2 = *(const float4*)(xr + 128 + iv);
  float4 c = *(const float4*)(ct + t * 128 + iv);
  float4 s = *(const float4*)(st + t * 128 + iv);
  ushort4 q1, q2, v1, v2;
  q1.x = f2bf(x1.x * c.x - x2.x * s.x);  q2.x = f2bf(x2.x * c.x + x1.x * s.x);
  q1.y = f2bf(x1.y * c.y - x2.y * s.y);  q2.y = f2bf(x2.y * c.y + x1.y * s.y);
  q1.z = f2bf(x1.z * c.z - x2.z * s.z);  q2.z = f2bf(x2.z * c.z + x1.z * s.z);
  q1.w = f2bf(x1.w * c.w - x2.w * s.w);  q2.w = f2bf(x2.w * c.w + x1.w * s.w);
  v1.x = f2bf(x1.x); v1.y = f2bf(x1.y); v1.z = f2bf(x1.z); v1.w = f2bf(x1.w);
  v2.x = f2bf(x2.x); v2.y = f2bf(x2.y); v2.z = f2bf(x2.z); v2.w = f2bf(x2.w);
  *(ushort4*)(qk + bt * DD + iv)       = q1;
  *(ushort4*)(qk + bt * DD + 128 + iv) = q2;
  *(ushort4*)(xv + bt * DD + iv)       = v1;
  *(ushort4*)(xv + bt * DD + 128 + iv) = v2;
}

// ---------------- MFMA sliding-window attention + fused LN ----------------
// 256 blocks x 512 threads (8 waves). Block: 64 queries, full key window.
// XCD-chunked block swizzle. Double-buffered LDS, one barrier per tile.
// Epilogue: 2 barriers, full-LDS Obuf combine, prefetched x residual.
__global__ void __launch_bounds__(512, 2) k_attn2(const u16* __restrict__ qk,
                                                  const u16* __restrict__ xv,
                                                  const float* __restrict__ x,
                                                  float* __restrict__ y,
                                                  const float* __restrict__ g,
                                                  const float* __restrict__ b,
                                                  u16* __restrict__ lnx,
                                                  int fuse){
  __shared__ char smem[131072];

  const int tid = threadIdx.x;
  const int lane = tid & 63;
  const int w = tid >> 6;
  const int qh = w >> 1, kh = w & 1;    // qh 0..3
  const int l15 = lane & 15, lg = lane >> 4;

  // XCD-aware chunked swizzle: 256 blocks, 8 XCDs, 32 blocks each (bijective)
  const int qg = (blockIdx.x & 7) * 32 + (blockIdx.x >> 3);
  const int qb = qg * 64;
  const int t0 = qb & (SEQL - 1);
  const size_t bbase = (size_t)(qb >> 13) << 13;

  // ---- preload Q B-frags (16 queries of this wave) ----
  uint4 qf[8];
  {
    const u16* qr = qk + (size_t)(qb + qh*16 + l15) * DD + lg*4;
    #pragma unroll
    for (int s = 0; s < 8; ++s){
      uint2 a = *(const uint2*)(qr + s*32);
      uint2 bq = *(const uint2*)(qr + s*32 + 16);
      qf[s] = make_uint4(a.x, a.y, bq.x, bq.y);
    }
  }

  f32x4 oacc[16];
  #pragma unroll
  for (int d = 0; d < 16; ++d) oacc[d] = (f32x4){0.f, 0.f, 0.f, 0.f};
  float lacc = 0.f;

  const int p0 = (t0 >= WSZ) ? (t0 - WSZ) : 0;
  const int ntile = ((t0 - p0) >> 6) + 1;

  const int sk15 = tid & 15, skt = (tid >> 4) & 3, sc = tid >> 6;   // K stage
  const int sdh = tid & 31, sk0 = (tid >> 5) * 4;                   // V stage
  const int vkhw = sk0 >> 5, vh = (sk0 >> 4) & 1, vlgw = (sk0 >> 2) & 3;

  uint4 kreg[4];
  uint  vreg[4][4];

  // ---- load tile 0 ----
  {
    const u16* sb = qk + (bbase + (size_t)p0 + skt*16 + sk15) * DD;
    #pragma unroll
    for (int u = 0; u < 4; ++u) kreg[u] = *(const uint4*)(sb + u*64 + sc*8);
    #pragma unroll
    for (int u = 0; u < 4; ++u){
      int d0 = sdh*2 + u*64;
      const u16* vb = xv + (bbase + (size_t)p0 + sk0) * DD + d0;
      vreg[u][0] = *(const uint*)(vb);
      vreg[u][1] = *(const uint*)(vb + DD);
      vreg[u][2] = *(const uint*)(vb + 2*DD);
      vreg[u][3] = *(const uint*)(vb + 3*DD);
    }
  }
  // ---- write tile 0 to buffer 0 ----
  #pragma unroll
  for (int u = 0; u < 4; ++u){
    int d0 = u*64 + sc*8;
    int s = d0 >> 5, r = d0 & 31;
    int h = r >> 4, lgw = (r & 15) >> 2;
    int rec = ((s*4 + skt)*4 + lgw)*16 + sk15;
    char* wp = smem + rec*16 + h*8;
    *(uint2*)wp         = make_uint2(kreg[u].x, kreg[u].y);
    *(uint2*)(wp + 256) = make_uint2(kreg[u].z, kreg[u].w);
  }
  #pragma unroll
  for (int u = 0; u < 4; ++u){
    int d0 = sdh*2 + u*64;
    uint a0 = vreg[u][0], a1 = vreg[u][1], a2 = vreg[u][2], a3 = vreg[u][3];
    uint w0 = (a0 & 0xffffu) | (a1 << 16);
    uint w1 = (a2 & 0xffffu) | (a3 << 16);
    uint w2 = (a0 >> 16) | (a1 & 0xffff0000u);
    uint w3 = (a2 >> 16) | (a3 & 0xffff0000u);
    int dimt = d0 >> 4, d15 = d0 & 15;
    int rec = ((dimt*2 + vkhw)*4 + vlgw)*16 + d15;
    char* wp = smem + 32768 + rec*16 + vh*8;
    *(uint2*)wp        = make_uint2(w0, w1);
    *(uint2*)(wp + 16) = make_uint2(w2, w3);
  }
  __syncthreads();

  int cur = 0;
  for (int ti = 0; ti < ntile; ++ti){
    const int p = p0 + ti*64;
    if (ti + 1 < ntile){
      const int pn = p + 64;
      const u16* sb = qk + (bbase + (size_t)pn + skt*16 + sk15) * DD;
      #pragma unroll
      for (int u = 0; u < 4; ++u) kreg[u] = *(const uint4*)(sb + u*64 + sc*8);
      #pragma unroll
      for (int u = 0; u < 4; ++u){
        int d0 = sdh*2 + u*64;
        const u16* vb = xv + (bbase + (size_t)pn + sk0) * DD + d0;
        vreg[u][0] = *(const uint*)(vb);
        vreg[u][1] = *(const uint*)(vb + DD);
        vreg[u][2] = *(const uint*)(vb + 2*DD);
        vreg[u][3] = *(const uint*)(vb + 3*DD);
      }
    }

    char* Klds = smem + cur*65536;
    char* Vlds = Klds + 32768;

    // --- S^T = K · Q^T ---
    f32x4 sacc[2];
    sacc[0] = (f32x4){0.f,0.f,0.f,0.f};
    sacc[1] = (f32x4){0.f,0.f,0.f,0.f};
    #pragma unroll
    for (int s = 0; s < 8; ++s){
      B8 ka0, ka1, qbf;
      ka0.b = *(const bf16x8*)(Klds + (((s*4 + kh*2+0)*4 + lg)*16 + l15)*16);
      ka1.b = *(const bf16x8*)(Klds + (((s*4 + kh*2+1)*4 + lg)*16 + l15)*16);
      qbf.u = qf[s];
      sacc[0] = __builtin_amdgcn_mfma_f32_16x16x32_bf16(ka0.b, qbf.b, sacc[0], 0, 0, 0);
      sacc[1] = __builtin_amdgcn_mfma_f32_16x16x32_bf16(ka1.b, qbf.b, sacc[1], 0, 0, 0);
    }

    // --- mask + exp + pack P^T -> PV A-frag ---
    B8 pa;
    #pragma unroll
    for (int ktp = 0; ktp < 2; ++ktp){
      int kbase = p + kh*32 + ktp*16 + lg*4;
      int qpos = t0 + qh*16 + l15;
      #pragma unroll
      for (int r = 0; r < 4; ++r){
        int kpos = kbase + r;
        float sv = sacc[ktp][r] * 0.0625f;
        bool ok = (kpos <= qpos) && (qpos <= kpos + WSZ);
        float pv = ok ? __expf(sv) : 0.0f;
        lacc += pv;
        pa.s[ktp*4 + r] = f2bf(pv);
      }
    }

    // --- O += P · V ---
    #pragma unroll
    for (int dimt = 0; dimt < 16; ++dimt){
      B8 vb;
      vb.b = *(const bf16x8*)(Vlds + (((dimt*2 + kh)*4 + lg)*16 + l15)*16);
      oacc[dimt] = __builtin_amdgcn_mfma_f32_16x16x32_bf16(pa.b, vb.b, oacc[dimt], 0, 0, 0);
    }

    // --- write prefetched tile into the OTHER buffer ---
    if (ti + 1 < ntile){
      char* nK = smem + (cur ^ 1)*65536;
      char* nV = nK + 32768;
      #pragma unroll
      for (int u = 0; u < 4; ++u){
        int d0 = u*64 + sc*8;
        int s = d0 >> 5, r = d0 & 31;
        int h = r >> 4, lgw = (r & 15) >> 2;
        int rec = ((s*4 + skt)*4 + lgw)*16 + sk15;
        char* wp = nK + rec*16 + h*8;
        *(uint2*)wp         = make_uint2(kreg[u].x, kreg[u].y);
        *(uint2*)(wp + 256) = make_uint2(kreg[u].z, kreg[u].w);
      }
      #pragma unroll
      for (int u = 0; u < 4; ++u){
        int d0 = sdh*2 + u*64;
        uint a0 = vreg[u][0], a1 = vreg[u][1], a2 = vreg[u][2], a3 = vreg[u][3];
        uint w0 = (a0 & 0xffffu) | (a1 << 16);
        uint w1 = (a2 & 0xffffu) | (a3 << 16);
        uint w2 = (a0 >> 16) | (a1 & 0xffff0000u);
        uint w3 = (a2 >> 16) | (a3 & 0xffff0000u);
        int dimt = d0 >> 4, d15 = d0 & 15;
        int rec = ((dimt*2 + vkhw)*4 + vlgw)*16 + d15;
        char* wp = nV + rec*16 + vh*8;
        *(uint2*)wp        = make_uint2(w0, w1);
        *(uint2*)(wp + 16) = make_uint2(w2, w3);
      }
    }
    __syncthreads();          // ONE barrier per tile
    cur ^= 1;
  }

  // ---- epilogue: 2 barriers, full-LDS combine, fused LN ----
  float* Obuf = (float*)smem;                 // [64][264] fp32 = 67.6 KB
  float* redl = (float*)(smem + 67584);       // 128 floats

  const int q = tid >> 3, dv = (tid & 7) * 4;
  float4 xrs[8];
  #pragma unroll
  for (int pass = 0; pass < 8; ++pass)
    xrs[pass] = *(const float4*)(x + (size_t)(qb + q)*DD + pass*32 + dv);

  lacc += __shfl_xor(lacc, 16, 64);
  lacc += __shfl_xor(lacc, 32, 64);
  if (lane < 16) redl[kh*64 + qh*16 + l15] = lacc;
  if (kh == 0){
    #pragma unroll
    for (int dimt = 0; dimt < 16; ++dimt)
      #pragma unroll
      for (int r = 0; r < 4; ++r)
        Obuf[(qh*16 + lg*4 + r)*264 + dimt*16 + l15] = oacc[dimt][r];
  }
  __syncthreads();
  if (kh == 1){
    #pragma unroll
    for (int dimt = 0; dimt < 16; ++dimt)
      #pragma unroll
      for (int r = 0; r < 4; ++r)
        Obuf[(qh*16 + lg*4 + r)*264 + dimt*16 + l15] += oacc[dimt][r];
  }
  __syncthreads();

  float inv = 1.0f / (redl[q] + redl[64 + q]);
  float4 ovs[8];
  float lsum = 0.f, lss = 0.f;
  #pragma unroll
  for (int pass = 0; pass < 8; ++pass){
    float4 o = *(float4*)&Obuf[q*264 + pass*32 + dv];
    float4 ov;
    ov.x = xrs[pass].x + o.x * inv;
    ov.y = xrs[pass].y + o.y * inv;
    ov.z = xrs[pass].z + o.z * inv;
    ov.w = xrs[pass].w + o.w * inv;
    *(float4*)(y + (size_t)(qb + q)*DD + pass*32 + dv) = ov;
    ovs[pass] = ov;
    lsum += ov.x + ov.y + ov.z + ov.w;
    lss  += ov.x*ov.x + ov.y*ov.y + ov.z*ov.z + ov.w*ov.w;
  }

  if (fuse){
    #pragma unroll
    for (int o = 1; o < 8; o <<= 1){
      lsum += __shfl_xor(lsum, o, 64);
      lss  += __shfl_xor(lss,  o, 64);
    }
    float m = lsum * (1.0f / DD);
    float var = lss * (1.0f / DD) - m * m;
    float rs = rsqrtf(var + 1e-5f);
    #pragma unroll
    for (int pass = 0; pass < 8; ++pass){
      float4 gf = *(const float4*)(g + pass*32 + dv);
      float4 bf = *(const float4*)(b + pass*32 + dv);
      ushort4 o4;
      o4.x = f2bf((ovs[pass].x - m) * rs * gf.x + bf.x);
      o4.y = f2bf((ovs[pass].y - m) * rs * gf.y + bf.y);
      o4.z = f2bf((ovs[pass].z - m) * rs * gf.z + bf.z);
      o4.w = f2bf((ovs[pass].w - m) * rs * gf.w + bf.w);
      *(ushort4*)(lnx + (size_t)(qb + q) * DD + pass*32 + dv) = o4;
    }
  }
}

// ---------------- layernorm (fallback when ws too small) ----------------
__global__ void __launch_bounds__(256) k_ln(const float* __restrict__ in,
                                            const float* __restrict__ g,
                                            const float* __restrict__ b,
                                            u16* __restrict__ out){
  int wid = (blockIdx.x * 256 + threadIdx.x) >> 6;
  int lane = threadIdx.x & 63;
  float4 v = *(const float4*)(in + wid * DD + lane * 4);
  float s = v.x + v.y + v.z + v.w;
  float ss = v.x * v.x + v.y * v.y + v.z * v.z + v.w * v.w;
  #pragma unroll
  for (int o = 32; o; o >>= 1){ s += __shfl_xor(s, o, 64); ss += __shfl_xor(ss, o, 64); }
  float m = s * (1.0f / DD);
  float var = ss * (1.0f / DD) - m * m;
  float rs = rsqrtf(var + 1e-5f);
  float4 gf = *(const float4*)(g + lane * 4);
  float4 bf = *(const float4*)(b + lane * 4);
  ushort4 o4;
  o4.x = f2bf((v.x - m) * rs * gf.x + bf.x);
  o4.y = f2bf((v.y - m) * rs * gf.y + bf.y);
  o4.z = f2bf((v.z - m) * rs * gf.z + bf.z);
  o4.w = f2bf((v.w - m) * rs * gf.w + bf.w);
  *(ushort4*)(out + wid * DD + lane * 4) = o4;
}

// -------- weight split: fp32 W[K][N] -> frag-major bf16 planes ----------
template<int KDIM, int NDIM>
__device__ __forceinline__ void split_one(const float* __restrict__ W,
                                          u16* __restrict__ Phi, int idx){
  int c15 = idx & 15;
  int lg = (idx >> 4) & 3;
  int nt = (idx >> 6) % (NDIM/16);
  int ks = idx / ((NDIM/16) * 64);
  int col = nt*16 + c15;
  B8 hi;
  #pragma unroll
  for (int j = 0; j < 8; ++j){
    int k = ks*32 + (j >> 2)*16 + lg*4 + (j & 3);
    hi.s[j] = f2bf(W[(size_t)k * NDIM + col]);
  }
  *(uint4*)(Phi + (size_t)idx * 8) = hi.u;
}

// all 6 layers at once: grid 1536
__global__ void __launch_bounds__(256) k_splitall(const float* __restrict__ w1,
                                                  const float* __restrict__ w2,
                                                  u16* __restrict__ P){
  int bk = blockIdx.x;              // 0..1535
  int L = bk >> 8, r = bk & 255;
  u16* PL = P + (size_t)L * 2 * PLN;
  if (r < 128) split_one<DD, HDIM>(w1 + (size_t)L*PLN, PL, r*256 + threadIdx.x);
  else         split_one<HDIM, DD>(w2 + (size_t)L*PLN, PL + PLN, (r-128)*256 + threadIdx.x);
}

// ---------------- MFMA GEMM: C = A(bf16) @ W(bf16 frag-major plane) ----------
// BM=128, BN=64, BK=64. 4 waves (2x2), 64x32 per wave. B via global_load_lds.
// XCD-pinned block mapping: m-tile -> XCD m/16 (aligned with attn token map).
// EPI 0: bias+GELU -> bf16 h. EPI 1: bias + residual -> fp32 x.
template<int KDIM, int NDIM, int EPI>
__global__ void __launch_bounds__(256, 4) k_gemm(const u16* __restrict__ A,
                                              const u16* __restrict__ BhG,
                                              const float* __restrict__ bias,
                                              const float* __restrict__ res,
                                              float* __restrict__ outf,
                                              u16* __restrict__ outh){
  __shared__ char smem[18432 + 8192];
  char* As = smem;                            // [128][144B] padded row-major
  char* Bs = smem + 18432;                    // 8 KB: [chunk][rec]

  const int tid = threadIdx.x;
  const int lane = tid & 63;
  const int w = tid >> 6;
  const int wr = w >> 1, wc = w & 1;
  const int l15 = lane & 15, lg = lane >> 4;
  const int lin = blockIdx.x;
  const int xcd = lin & 7;
  const int idx = lin >> 3;
  const int m0 = (xcd * 16 + (idx & 15)) * 128;
  const int n0 = (idx >> 4) * 64;
  const int NT16 = NDIM / 16;

  f32x4 acc[4][2];
  #pragma unroll
  for (int a = 0; a < 4; ++a){
    acc[a][0] = (f32x4){0.f,0.f,0.f,0.f};
    acc[a][1] = (f32x4){0.f,0.f,0.f,0.f};
  }

  for (int kb = 0; kb < KDIM/64; ++kb){
    __syncthreads();
    #pragma unroll
    for (int p = 0; p < 4; ++p){
      int c = p*256 + tid;
      int row = c >> 3, cc = c & 7;
      uint4 v = *(const uint4*)(A + (size_t)(m0 + row) * KDIM + kb*64 + cc*8);
      *(uint4*)(As + row*144 + cc*16) = v;
    }
    #pragma unroll
    for (int p = 0; p < 2; ++p){
      int j = p*256 + tid;                       // 0..511
      int chunk = j >> 6, r = j & 63;            // chunk = s*4 + ntl
      const u16* src = BhG
          + (((size_t)(kb*2 + (chunk >> 2)) * NT16 + (n0 >> 4) + (chunk & 3))*64 + r)*8;
      gload16(src, Bs + j*16);
    }
    __syncthreads();

    #pragma unroll
    for (int s = 0; s < 2; ++s){
      B8 af[4], bhf[2];
      #pragma unroll
      for (int a = 0; a < 4; ++a){
        const char* ab = As + (wr*64 + a*16 + l15)*144 + s*64 + lg*8;
        uint2 lo = *(const uint2*)ab;
        uint2 hi = *(const uint2*)(ab + 32);
        af[a].u = make_uint4(lo.x, lo.y, hi.x, hi.y);
      }
      #pragma unroll
      for (int c = 0; c < 2; ++c){
        int off = (((s*4 + wc*2 + c)*64) + lg*16 + l15)*16;
        bhf[c].u = *(const uint4*)(Bs + off);
      }
      #pragma unroll
      for (int a = 0; a < 4; ++a)
        #pragma unroll
        for (int c = 0; c < 2; ++c)
          acc[a][c] = __builtin_amdgcn_mfma_f32_16x16x32_bf16(af[a].b, bhf[c].b, acc[a][c], 0, 0, 0);
    }
  }

  float bv[2];
  bv[0] = bias[n0 + wc*32 + l15];
  bv[1] = bias[n0 + wc*32 + 16 + l15];

  #pragma unroll
  for (int a = 0; a < 4; ++a){
    #pragma unroll
    for (int c = 0; c < 2; ++c){
      #pragma unroll
      for (int r = 0; r < 4; ++r){
        int row = m0 + wr*64 + a*16 + lg*4 + r;
        int col = n0 + wc*32 + c*16 + l15;
        float v = acc[a][c][r] + bv[c];
        if (EPI == 0){
          float gl = 0.5f * v * (1.0f + erff(v * 0.70710678f));
          outh[(size_t)row * NDIM + col] = f2bf(gl);
        } else {
          outf[(size_t)row * NDIM + col] = v + res[(size_t)row * NDIM + col];
        }
      }
    }
  }
}

// ---------------- final LN + (256x32) projection, fp32 out, XCD-chunked ------
__global__ void __launch_bounds__(256) k_final(const float* __restrict__ x,
                                               const float* __restrict__ g,
                                               const float* __restrict__ b,
                                               const float* __restrict__ wout,
                                               const float* __restrict__ bout,
                                               float* __restrict__ out){
  __shared__ float lds[4][256];
  int vbid = (blockIdx.x & 7) * 512 + (blockIdx.x >> 3);   // 4096 blocks
  int widx = threadIdx.x >> 6, lane = threadIdx.x & 63;
  int bt = vbid * 4 + widx;
  float4 v = *(const float4*)(x + bt * DD + lane * 4);
  float s = v.x + v.y + v.z + v.w;
  float ss = v.x * v.x + v.y * v.y + v.z * v.z + v.w * v.w;
  #pragma unroll
  for (int o = 32; o; o >>= 1){ s += __shfl_xor(s, o, 64); ss += __shfl_xor(ss, o, 64); }
  float m = s * (1.0f / DD);
  float var = ss * (1.0f / DD) - m * m;
  float rs = rsqrtf(var + 1e-5f);
  float4 gf = *(const float4*)(g + lane * 4);
  float4 bf = *(const float4*)(b + lane * 4);
  lds[widx][lane * 4 + 0] = (v.x - m) * rs * gf.x + bf.x;
  lds[widx][lane * 4 + 1] = (v.y - m) * rs * gf.y + bf.y;
  lds[widx][lane * 4 + 2] = (v.z - m) * rs * gf.z + bf.z;
  lds[widx][lane * 4 + 3] = (v.w - m) * rs * gf.w + bf.w;
  __syncthreads();
  int vo = lane & 31, half = lane >> 5;
  const float* lp = &lds[widx][half * 128];
  const float* wp = wout + half * 128 * NVOCAB + vo;
  float acc = 0;
  #pragma unroll 4
  for (int d = 0; d < 128; ++d) acc += lp[d] * wp[d * NVOCAB];
  acc += __shfl_down(acc, 32, 64);
  if (lane < 32) out[bt * NVOCAB + vo] = acc + bout[vo];
}

extern "C" void kernel_launch(void* const* d_in, const int* in_sizes, int n_in,
                              void* d_out, int out_size, void* d_ws, size_t ws_size,
                              hipStream_t stream) {
  const int*   tokens = (const int*)d_in[0];
  const float* emb   = (const float*)d_in[1];
  const float* ffs   = (const float*)d_in[2];
  const float* ffb   = (const float*)d_in[3];
  const float* w1    = (const float*)d_in[4];
  const float* b1    = (const float*)d_in[5];
  const float* w2    = (const float*)d_in[6];
  const float* b2    = (const float*)d_in[7];
  const float* lnfs  = (const float*)d_in[8];
  const float* lnfb  = (const float*)d_in[9];
  const float* wout  = (const float*)d_in[10];
  const float* bout  = (const float*)d_in[11];
  float* out = (float*)d_out;

  char* ws = (char*)d_ws;
  float* x    = (float*)(ws);                         // 16 MB fp32
  float* y    = (float*)(ws + (size_t)16*1024*1024);  // 16 MB fp32
  u16*   buf8 = (u16*)  (ws + (size_t)32*1024*1024);  //  8 MB bf16 (xv)
  u16*   qk   = (u16*)  (ws + (size_t)40*1024*1024);  //  8 MB bf16
  u16*   pln  = (u16*)  (ws + (size_t)48*1024*1024);  //  6 MB (12 planes)
  u16*   h    = (u16*)  (ws + (size_t)56*1024*1024);  // 32 MB bf16 (56..88)

  float* ct = (float*)(ws + (size_t)96*1024*1024);    // 96..100 (bigws)
  float* st = (float*)(ws + (size_t)100*1024*1024);   // 100..104 (bigws)
  const int bigws = (ws_size >= (size_t)104*1024*1024) ? 1 : 0;
  if (!bigws){
    ct = (float*)(ws + (size_t)48*1024*1024);          // 48..52 (pln unused then)
    st = (float*)(ws + (size_t)52*1024*1024);          // 52..56
  }
  const int fuse = (ws_size >= (size_t)96*1024*1024) ? 1 : 0;
  u16* lnx = fuse ? (u16*)(ws + (size_t)88*1024*1024) : buf8; // bf16, 8 MB

  k_tables<<<4096, 256, 0, stream>>>(ct, st);
  k_embed<<<4096, 256, 0, stream>>>(tokens, emb, x);
  if (bigws) k_splitall<<<1536, 256, 0, stream>>>(w1, w2, pln);
  for (int L = 0; L < NLAYER; ++L){
    k_rope<<<2048, 256, 0, stream>>>(x, ct, st, qk, buf8);
    k_attn2<<<256, 512, 0, stream>>>(qk, buf8, x, y,
                                     ffs + L*DD, ffb + L*DD, lnx, fuse);
    if (!fuse)
      k_ln<<<4096, 256, 0, stream>>>(y, ffs + L*DD, ffb + L*DD, lnx);
    const u16* PL;
    if (bigws){
      PL = pln + (size_t)L*2*PLN;
    } else {
      k_splitall<<<256, 256, 0, stream>>>(w1 + (size_t)L*PLN, w2 + (size_t)L*PLN, qk);
      PL = qk;
    }
    k_gemm<DD, HDIM, 0><<<2048, 256, 0, stream>>>(
        lnx, PL, b1 + L*HDIM, nullptr, nullptr, h);
    k_gemm<HDIM, DD, 1><<<512, 256, 0, stream>>>(
        h, PL + PLN, b2 + L*DD, y, x, nullptr);
  }
  k_final<<<4096, 256, 0, stream>>>(x, lnfs, lnfb, wout, bout, out);
}

// Round 20
// 664.732 us; speedup vs baseline: 1.4217x; 1.0167x over previous
//
#include <hip/hip_runtime.h>
#include <hip/hip_bf16.h>
#include <math.h>

#define BATCH 2
#define SEQL 8192
#define DD 256
#define HDIM 1024
#define NLAYER 6
#define WSZ 512
#define NVOCAB 32
#define NTOK (BATCH*SEQL)
#define PLN (DD*HDIM)   // 262144 elems per weight plane

typedef unsigned short u16;
typedef __attribute__((ext_vector_type(8))) short bf16x8;
typedef __attribute__((ext_vector_type(4))) float f32x4;

union B8 { uint4 u; bf16x8 b; ushort s[8]; uint w[4]; };

__device__ inline float bf2f(u16 v){
  unsigned int u = ((unsigned int)v) << 16;
  return __uint_as_float(u);
}
__device__ inline u16 f2bf(float f){
  unsigned int u = __float_as_uint(f);
  u += 0x7fff + ((u >> 16) & 1);   // RNE
  return (u16)(u >> 16);
}

__device__ __forceinline__ void gload16(const void* g, void* l){
  __builtin_amdgcn_global_load_lds(
      (const __attribute__((address_space(1))) unsigned int*)g,
      (__attribute__((address_space(3))) unsigned int*)l, 16, 0, 0);
}

// ------- init: rope table (packed bf16 cos|sin) + embedding gather ----------
__global__ void k_init(const int* __restrict__ tokens, const float* __restrict__ emb,
                       float* __restrict__ x, uint* __restrict__ cs){
  if (blockIdx.x < 4096){
    int idx = blockIdx.x * 256 + threadIdx.x;   // t*128 + i
    int t = idx >> 7, i = idx & 127;
    float freq = expf(-((float)i / 128.0f) * 9.210340371976184f);  // ln(10000)
    float fr = (float)t * freq;
    uint c = (uint)f2bf(cosf(fr));
    uint s = (uint)f2bf(sinf(fr));
    cs[idx] = c | (s << 16);
  } else {
    int vbid = blockIdx.x - 4096;               // 4096 blocks
    int idx = vbid * 256 + threadIdx.x;         // bt*64 + dvec
    int bt = idx >> 6, dv = (idx & 63) << 2;
    int tok = tokens[bt];
    *(float4*)(x + bt * DD + dv) = *(const float4*)(emb + tok * DD + dv);
  }
}

// ------- rope: x(fp32) -> qk (roped bf16) and xv (bf16 copy), XCD-chunked ----
__global__ void k_rope(const float* __restrict__ x, const uint* __restrict__ cs,
                       u16* __restrict__ qk, u16* __restrict__ xv){
  int vbid = (blockIdx.x & 7) * 256 + (blockIdx.x >> 3);   // 2048 blocks
  int idx = vbid * 256 + threadIdx.x;           // bt*32 + ivec  (half-dim /4)
  int bt = idx >> 5, iv = (idx & 31) << 2;
  int t = bt & (SEQL - 1);
  const float* xr = x + bt * DD;
  float4 x1 = *(const float4*)(xr + iv);
  float4 x2 = *(const float4*)(xr + 128 + iv);
  uint4 p = *(const uint4*)(cs + t * 128 + iv);
  float c0 = bf2f((u16)(p.x & 0xffff)), s0 = bf2f((u16)(p.x >> 16));
  float c1 = bf2f((u16)(p.y & 0xffff)), s1 = bf2f((u16)(p.y >> 16));
  float c2 = bf2f((u16)(p.z & 0xffff)), s2 = bf2f((u16)(p.z >> 16));
  float c3 = bf2f((u16)(p.w & 0xffff)), s3 = bf2f((u16)(p.w >> 16));
  ushort4 q1, q2, v1, v2;
  q1.x = f2bf(x1.x * c0 - x2.x * s0);  q2.x = f2bf(x2.x * c0 + x1.x * s0);
  q1.y = f2bf(x1.y * c1 - x2.y * s1);  q2.y = f2bf(x2.y * c1 + x1.y * s1);
  q1.z = f2bf(x1.z * c2 - x2.z * s2);  q2.z = f2bf(x2.z * c2 + x1.z * s2);
  q1.w = f2bf(x1.w * c3 - x2.w * s3);  q2.w = f2bf(x2.w * c3 + x1.w * s3);
  v1.x = f2bf(x1.x); v1.y = f2bf(x1.y); v1.z = f2bf(x1.z); v1.w = f2bf(x1.w);
  v2.x = f2bf(x2.x); v2.y = f2bf(x2.y); v2.z = f2bf(x2.z); v2.w = f2bf(x2.w);
  *(ushort4*)(qk + bt * DD + iv)       = q1;
  *(ushort4*)(qk + bt * DD + 128 + iv) = q2;
  *(ushort4*)(xv + bt * DD + iv)       = v1;
  *(ushort4*)(xv + bt * DD + 128 + iv) = v2;
}

// ---------------- MFMA sliding-window attention + fused LN ----------------
// 256 blocks x 512 threads (8 waves). Block: 64 queries, full key window.
// XCD-chunked block swizzle. Double-buffered LDS, one barrier per tile.
// Epilogue: 2 barriers, full-LDS Obuf combine, prefetched x residual.
// y written as bf16 (residual stream for gemm2).
__global__ void __launch_bounds__(512, 2) k_attn2(const u16* __restrict__ qk,
                                                  const u16* __restrict__ xv,
                                                  const float* __restrict__ x,
                                                  u16* __restrict__ yb,
                                                  const float* __restrict__ g,
                                                  const float* __restrict__ b,
                                                  u16* __restrict__ lnx,
                                                  int fuse){
  __shared__ char smem[131072];

  const int tid = threadIdx.x;
  const int lane = tid & 63;
  const int w = tid >> 6;
  const int qh = w >> 1, kh = w & 1;    // qh 0..3
  const int l15 = lane & 15, lg = lane >> 4;

  // XCD-aware chunked swizzle: 256 blocks, 8 XCDs, 32 blocks each (bijective)
  const int qg = (blockIdx.x & 7) * 32 + (blockIdx.x >> 3);
  const int qb = qg * 64;
  const int t0 = qb & (SEQL - 1);
  const size_t bbase = (size_t)(qb >> 13) << 13;

  // ---- preload Q B-frags (16 queries of this wave) ----
  uint4 qf[8];
  {
    const u16* qr = qk + (size_t)(qb + qh*16 + l15) * DD + lg*4;
    #pragma unroll
    for (int s = 0; s < 8; ++s){
      uint2 a = *(const uint2*)(qr + s*32);
      uint2 bq = *(const uint2*)(qr + s*32 + 16);
      qf[s] = make_uint4(a.x, a.y, bq.x, bq.y);
    }
  }

  f32x4 oacc[16];
  #pragma unroll
  for (int d = 0; d < 16; ++d) oacc[d] = (f32x4){0.f, 0.f, 0.f, 0.f};
  float lacc = 0.f;

  const int p0 = (t0 >= WSZ) ? (t0 - WSZ) : 0;
  const int ntile = ((t0 - p0) >> 6) + 1;

  const int sk15 = tid & 15, skt = (tid >> 4) & 3, sc = tid >> 6;   // K stage
  const int sdh = tid & 31, sk0 = (tid >> 5) * 4;                   // V stage
  const int vkhw = sk0 >> 5, vh = (sk0 >> 4) & 1, vlgw = (sk0 >> 2) & 3;

  uint4 kreg[4];
  uint  vreg[4][4];

  // ---- load tile 0 ----
  {
    const u16* sb = qk + (bbase + (size_t)p0 + skt*16 + sk15) * DD;
    #pragma unroll
    for (int u = 0; u < 4; ++u) kreg[u] = *(const uint4*)(sb + u*64 + sc*8);
    #pragma unroll
    for (int u = 0; u < 4; ++u){
      int d0 = sdh*2 + u*64;
      const u16* vb = xv + (bbase + (size_t)p0 + sk0) * DD + d0;
      vreg[u][0] = *(const uint*)(vb);
      vreg[u][1] = *(const uint*)(vb + DD);
      vreg[u][2] = *(const uint*)(vb + 2*DD);
      vreg[u][3] = *(const uint*)(vb + 3*DD);
    }
  }
  // ---- write tile 0 to buffer 0 ----
  #pragma unroll
  for (int u = 0; u < 4; ++u){
    int d0 = u*64 + sc*8;
    int s = d0 >> 5, r = d0 & 31;
    int h = r >> 4, lgw = (r & 15) >> 2;
    int rec = ((s*4 + skt)*4 + lgw)*16 + sk15;
    char* wp = smem + rec*16 + h*8;
    *(uint2*)wp         = make_uint2(kreg[u].x, kreg[u].y);
    *(uint2*)(wp + 256) = make_uint2(kreg[u].z, kreg[u].w);
  }
  #pragma unroll
  for (int u = 0; u < 4; ++u){
    int d0 = sdh*2 + u*64;
    uint a0 = vreg[u][0], a1 = vreg[u][1], a2 = vreg[u][2], a3 = vreg[u][3];
    uint w0 = (a0 & 0xffffu) | (a1 << 16);
    uint w1 = (a2 & 0xffffu) | (a3 << 16);
    uint w2 = (a0 >> 16) | (a1 & 0xffff0000u);
    uint w3 = (a2 >> 16) | (a3 & 0xffff0000u);
    int dimt = d0 >> 4, d15 = d0 & 15;
    int rec = ((dimt*2 + vkhw)*4 + vlgw)*16 + d15;
    char* wp = smem + 32768 + rec*16 + vh*8;
    *(uint2*)wp        = make_uint2(w0, w1);
    *(uint2*)(wp + 16) = make_uint2(w2, w3);
  }
  __syncthreads();

  int cur = 0;
  for (int ti = 0; ti < ntile; ++ti){
    const int p = p0 + ti*64;
    if (ti + 1 < ntile){
      const int pn = p + 64;
      const u16* sb = qk + (bbase + (size_t)pn + skt*16 + sk15) * DD;
      #pragma unroll
      for (int u = 0; u < 4; ++u) kreg[u] = *(const uint4*)(sb + u*64 + sc*8);
      #pragma unroll
      for (int u = 0; u < 4; ++u){
        int d0 = sdh*2 + u*64;
        const u16* vb = xv + (bbase + (size_t)pn + sk0) * DD + d0;
        vreg[u][0] = *(const uint*)(vb);
        vreg[u][1] = *(const uint*)(vb + DD);
        vreg[u][2] = *(const uint*)(vb + 2*DD);
        vreg[u][3] = *(const uint*)(vb + 3*DD);
      }
    }

    char* Klds = smem + cur*65536;
    char* Vlds = Klds + 32768;

    // --- S^T = K · Q^T ---
    f32x4 sacc[2];
    sacc[0] = (f32x4){0.f,0.f,0.f,0.f};
    sacc[1] = (f32x4){0.f,0.f,0.f,0.f};
    #pragma unroll
    for (int s = 0; s < 8; ++s){
      B8 ka0, ka1, qbf;
      ka0.b = *(const bf16x8*)(Klds + (((s*4 + kh*2+0)*4 + lg)*16 + l15)*16);
      ka1.b = *(const bf16x8*)(Klds + (((s*4 + kh*2+1)*4 + lg)*16 + l15)*16);
      qbf.u = qf[s];
      sacc[0] = __builtin_amdgcn_mfma_f32_16x16x32_bf16(ka0.b, qbf.b, sacc[0], 0, 0, 0);
      sacc[1] = __builtin_amdgcn_mfma_f32_16x16x32_bf16(ka1.b, qbf.b, sacc[1], 0, 0, 0);
    }

    // --- mask + exp + pack P^T -> PV A-frag ---
    B8 pa;
    #pragma unroll
    for (int ktp = 0; ktp < 2; ++ktp){
      int kbase = p + kh*32 + ktp*16 + lg*4;
      int qpos = t0 + qh*16 + l15;
      #pragma unroll
      for (int r = 0; r < 4; ++r){
        int kpos = kbase + r;
        float sv = sacc[ktp][r] * 0.0625f;
        bool ok = (kpos <= qpos) && (qpos <= kpos + WSZ);
        float pv = ok ? __expf(sv) : 0.0f;
        lacc += pv;
        pa.s[ktp*4 + r] = f2bf(pv);
      }
    }

    // --- O += P · V ---
    #pragma unroll
    for (int dimt = 0; dimt < 16; ++dimt){
      B8 vb;
      vb.b = *(const bf16x8*)(Vlds + (((dimt*2 + kh)*4 + lg)*16 + l15)*16);
      oacc[dimt] = __builtin_amdgcn_mfma_f32_16x16x32_bf16(pa.b, vb.b, oacc[dimt], 0, 0, 0);
    }

    // --- write prefetched tile into the OTHER buffer ---
    if (ti + 1 < ntile){
      char* nK = smem + (cur ^ 1)*65536;
      char* nV = nK + 32768;
      #pragma unroll
      for (int u = 0; u < 4; ++u){
        int d0 = u*64 + sc*8;
        int s = d0 >> 5, r = d0 & 31;
        int h = r >> 4, lgw = (r & 15) >> 2;
        int rec = ((s*4 + skt)*4 + lgw)*16 + sk15;
        char* wp = nK + rec*16 + h*8;
        *(uint2*)wp         = make_uint2(kreg[u].x, kreg[u].y);
        *(uint2*)(wp + 256) = make_uint2(kreg[u].z, kreg[u].w);
      }
      #pragma unroll
      for (int u = 0; u < 4; ++u){
        int d0 = sdh*2 + u*64;
        uint a0 = vreg[u][0], a1 = vreg[u][1], a2 = vreg[u][2], a3 = vreg[u][3];
        uint w0 = (a0 & 0xffffu) | (a1 << 16);
        uint w1 = (a2 & 0xffffu) | (a3 << 16);
        uint w2 = (a0 >> 16) | (a1 & 0xffff0000u);
        uint w3 = (a2 >> 16) | (a3 & 0xffff0000u);
        int dimt = d0 >> 4, d15 = d0 & 15;
        int rec = ((dimt*2 + vkhw)*4 + vlgw)*16 + d15;
        char* wp = nV + rec*16 + vh*8;
        *(uint2*)wp        = make_uint2(w0, w1);
        *(uint2*)(wp + 16) = make_uint2(w2, w3);
      }
    }
    __syncthreads();          // ONE barrier per tile
    cur ^= 1;
  }

  // ---- epilogue: 2 barriers, full-LDS combine, fused LN ----
  float* Obuf = (float*)smem;                 // [64][264] fp32 = 67.6 KB
  float* redl = (float*)(smem + 67584);       // 128 floats

  const int q = tid >> 3, dv = (tid & 7) * 4;
  float4 xrs[8];
  #pragma unroll
  for (int pass = 0; pass < 8; ++pass)
    xrs[pass] = *(const float4*)(x + (size_t)(qb + q)*DD + pass*32 + dv);

  lacc += __shfl_xor(lacc, 16, 64);
  lacc += __shfl_xor(lacc, 32, 64);
  if (lane < 16) redl[kh*64 + qh*16 + l15] = lacc;
  if (kh == 0){
    #pragma unroll
    for (int dimt = 0; dimt < 16; ++dimt)
      #pragma unroll
      for (int r = 0; r < 4; ++r)
        Obuf[(qh*16 + lg*4 + r)*264 + dimt*16 + l15] = oacc[dimt][r];
  }
  __syncthreads();
  if (kh == 1){
    #pragma unroll
    for (int dimt = 0; dimt < 16; ++dimt)
      #pragma unroll
      for (int r = 0; r < 4; ++r)
        Obuf[(qh*16 + lg*4 + r)*264 + dimt*16 + l15] += oacc[dimt][r];
  }
  __syncthreads();

  float inv = 1.0f / (redl[q] + redl[64 + q]);
  float4 ovs[8];
  float lsum = 0.f, lss = 0.f;
  #pragma unroll
  for (int pass = 0; pass < 8; ++pass){
    float4 o = *(float4*)&Obuf[q*264 + pass*32 + dv];
    float4 ov;
    ov.x = xrs[pass].x + o.x * inv;
    ov.y = xrs[pass].y + o.y * inv;
    ov.z = xrs[pass].z + o.z * inv;
    ov.w = xrs[pass].w + o.w * inv;
    ushort4 yv;
    yv.x = f2bf(ov.x); yv.y = f2bf(ov.y); yv.z = f2bf(ov.z); yv.w = f2bf(ov.w);
    *(ushort4*)(yb + (size_t)(qb + q)*DD + pass*32 + dv) = yv;
    ovs[pass] = ov;
    lsum += ov.x + ov.y + ov.z + ov.w;
    lss  += ov.x*ov.x + ov.y*ov.y + ov.z*ov.z + ov.w*ov.w;
  }

  if (fuse){
    #pragma unroll
    for (int o = 1; o < 8; o <<= 1){
      lsum += __shfl_xor(lsum, o, 64);
      lss  += __shfl_xor(lss,  o, 64);
    }
    float m = lsum * (1.0f / DD);
    float var = lss * (1.0f / DD) - m * m;
    float rs = rsqrtf(var + 1e-5f);
    #pragma unroll
    for (int pass = 0; pass < 8; ++pass){
      float4 gf = *(const float4*)(g + pass*32 + dv);
      float4 bf = *(const float4*)(b + pass*32 + dv);
      ushort4 o4;
      o4.x = f2bf((ovs[pass].x - m) * rs * gf.x + bf.x);
      o4.y = f2bf((ovs[pass].y - m) * rs * gf.y + bf.y);
      o4.z = f2bf((ovs[pass].z - m) * rs * gf.z + bf.z);
      o4.w = f2bf((ovs[pass].w - m) * rs * gf.w + bf.w);
      *(ushort4*)(lnx + (size_t)(qb + q) * DD + pass*32 + dv) = o4;
    }
  }
}

// ---------------- layernorm (fallback when ws too small), bf16 in ------------
__global__ void __launch_bounds__(256) k_ln(const u16* __restrict__ in,
                                            const float* __restrict__ g,
                                            const float* __restrict__ b,
                                            u16* __restrict__ out){
  int wid = (blockIdx.x * 256 + threadIdx.x) >> 6;
  int lane = threadIdx.x & 63;
  ushort4 i4 = *(const ushort4*)(in + (size_t)wid * DD + lane * 4);
  float4 v = make_float4(bf2f(i4.x), bf2f(i4.y), bf2f(i4.z), bf2f(i4.w));
  float s = v.x + v.y + v.z + v.w;
  float ss = v.x * v.x + v.y * v.y + v.z * v.z + v.w * v.w;
  #pragma unroll
  for (int o = 32; o; o >>= 1){ s += __shfl_xor(s, o, 64); ss += __shfl_xor(ss, o, 64); }
  float m = s * (1.0f / DD);
  float var = ss * (1.0f / DD) - m * m;
  float rs = rsqrtf(var + 1e-5f);
  float4 gf = *(const float4*)(g + lane * 4);
  float4 bf = *(const float4*)(b + lane * 4);
  ushort4 o4;
  o4.x = f2bf((v.x - m) * rs * gf.x + bf.x);
  o4.y = f2bf((v.y - m) * rs * gf.y + bf.y);
  o4.z = f2bf((v.z - m) * rs * gf.z + bf.z);
  o4.w = f2bf((v.w - m) * rs * gf.w + bf.w);
  *(ushort4*)(out + (size_t)wid * DD + lane * 4) = o4;
}

// -------- weight split: fp32 W[K][N] -> frag-major bf16 planes ----------
template<int KDIM, int NDIM>
__device__ __forceinline__ void split_one(const float* __restrict__ W,
                                          u16* __restrict__ Phi, int idx){
  int c15 = idx & 15;
  int lg = (idx >> 4) & 3;
  int nt = (idx >> 6) % (NDIM/16);
  int ks = idx / ((NDIM/16) * 64);
  int col = nt*16 + c15;
  B8 hi;
  #pragma unroll
  for (int j = 0; j < 8; ++j){
    int k = ks*32 + (j >> 2)*16 + lg*4 + (j & 3);
    hi.s[j] = f2bf(W[(size_t)k * NDIM + col]);
  }
  *(uint4*)(Phi + (size_t)idx * 8) = hi.u;
}

// all 6 layers at once: grid 1536
__global__ void __launch_bounds__(256) k_splitall(const float* __restrict__ w1,
                                                  const float* __restrict__ w2,
                                                  u16* __restrict__ P){
  int bk = blockIdx.x;              // 0..1535
  int L = bk >> 8, r = bk & 255;
  u16* PL = P + (size_t)L * 2 * PLN;
  if (r < 128) split_one<DD, HDIM>(w1 + (size_t)L*PLN, PL, r*256 + threadIdx.x);
  else         split_one<HDIM, DD>(w2 + (size_t)L*PLN, PL + PLN, (r-128)*256 + threadIdx.x);
}

// ---------------- MFMA GEMM: C = A(bf16) @ W(bf16 frag-major plane) ----------
// BM=128, BN=64, BK=64. 4 waves (2x2), 64x32 per wave. B via global_load_lds.
// XCD-pinned block mapping: m-tile -> XCD m/16 (aligned with attn token map).
// EPI 0: bias+GELU -> bf16 h. EPI 1: bias + residual(bf16) -> fp32 x.
template<int KDIM, int NDIM, int EPI>
__global__ void __launch_bounds__(256, 4) k_gemm(const u16* __restrict__ A,
                                              const u16* __restrict__ BhG,
                                              const float* __restrict__ bias,
                                              const u16* __restrict__ res,
                                              float* __restrict__ outf,
                                              u16* __restrict__ outh){
  __shared__ char smem[18432 + 8192];
  char* As = smem;                            // [128][144B] padded row-major
  char* Bs = smem + 18432;                    // 8 KB: [chunk][rec]

  const int tid = threadIdx.x;
  const int lane = tid & 63;
  const int w = tid >> 6;
  const int wr = w >> 1, wc = w & 1;
  const int l15 = lane & 15, lg = lane >> 4;
  const int lin = blockIdx.x;
  const int xcd = lin & 7;
  const int idx = lin >> 3;
  const int m0 = (xcd * 16 + (idx & 15)) * 128;
  const int n0 = (idx >> 4) * 64;
  const int NT16 = NDIM / 16;

  f32x4 acc[4][2];
  #pragma unroll
  for (int a = 0; a < 4; ++a){
    acc[a][0] = (f32x4){0.f,0.f,0.f,0.f};
    acc[a][1] = (f32x4){0.f,0.f,0.f,0.f};
  }

  for (int kb = 0; kb < KDIM/64; ++kb){
    __syncthreads();
    #pragma unroll
    for (int p = 0; p < 4; ++p){
      int c = p*256 + tid;
      int row = c >> 3, cc = c & 7;
      uint4 v = *(const uint4*)(A + (size_t)(m0 + row) * KDIM + kb*64 + cc*8);
      *(uint4*)(As + row*144 + cc*16) = v;
    }
    #pragma unroll
    for (int p = 0; p < 2; ++p){
      int j = p*256 + tid;                       // 0..511
      int chunk = j >> 6, r = j & 63;            // chunk = s*4 + ntl
      const u16* src = BhG
          + (((size_t)(kb*2 + (chunk >> 2)) * NT16 + (n0 >> 4) + (chunk & 3))*64 + r)*8;
      gload16(src, Bs + j*16);
    }
    __syncthreads();

    #pragma unroll
    for (int s = 0; s < 2; ++s){
      B8 af[4], bhf[2];
      #pragma unroll
      for (int a = 0; a < 4; ++a){
        const char* ab = As + (wr*64 + a*16 + l15)*144 + s*64 + lg*8;
        uint2 lo = *(const uint2*)ab;
        uint2 hi = *(const uint2*)(ab + 32);
        af[a].u = make_uint4(lo.x, lo.y, hi.x, hi.y);
      }
      #pragma unroll
      for (int c = 0; c < 2; ++c){
        int off = (((s*4 + wc*2 + c)*64) + lg*16 + l15)*16;
        bhf[c].u = *(const uint4*)(Bs + off);
      }
      #pragma unroll
      for (int a = 0; a < 4; ++a)
        #pragma unroll
        for (int c = 0; c < 2; ++c)
          acc[a][c] = __builtin_amdgcn_mfma_f32_16x16x32_bf16(af[a].b, bhf[c].b, acc[a][c], 0, 0, 0);
    }
  }

  float bv[2];
  bv[0] = bias[n0 + wc*32 + l15];
  bv[1] = bias[n0 + wc*32 + 16 + l15];

  #pragma unroll
  for (int a = 0; a < 4; ++a){
    #pragma unroll
    for (int c = 0; c < 2; ++c){
      #pragma unroll
      for (int r = 0; r < 4; ++r){
        int row = m0 + wr*64 + a*16 + lg*4 + r;
        int col = n0 + wc*32 + c*16 + l15;
        float v = acc[a][c][r] + bv[c];
        if (EPI == 0){
          float gl = 0.5f * v * (1.0f + erff(v * 0.70710678f));
          outh[(size_t)row * NDIM + col] = f2bf(gl);
        } else {
          outf[(size_t)row * NDIM + col] = v + bf2f(res[(size_t)row * NDIM + col]);
        }
      }
    }
  }
}

// ---------------- final LN + (256x32) projection, fp32 out, XCD-chunked ------
__global__ void __launch_bounds__(256) k_final(const float* __restrict__ x,
                                               const float* __restrict__ g,
                                               const float* __restrict__ b,
                                               const float* __restrict__ wout,
                                               const float* __restrict__ bout,
                                               float* __restrict__ out){
  __shared__ float lds[4][256];
  int vbid = (blockIdx.x & 7) * 512 + (blockIdx.x >> 3);   // 4096 blocks
  int widx = threadIdx.x >> 6, lane = threadIdx.x & 63;
  int bt = vbid * 4 + widx;
  float4 v = *(const float4*)(x + bt * DD + lane * 4);
  float s = v.x + v.y + v.z + v.w;
  float ss = v.x * v.x + v.y * v.y + v.z * v.z + v.w * v.w;
  #pragma unroll
  for (int o = 32; o; o >>= 1){ s += __shfl_xor(s, o, 64); ss += __shfl_xor(ss, o, 64); }
  float m = s * (1.0f / DD);
  float var = ss * (1.0f / DD) - m * m;
  float rs = rsqrtf(var + 1e-5f);
  float4 gf = *(const float4*)(g + lane * 4);
  float4 bf = *(const float4*)(b + lane * 4);
  lds[widx][lane * 4 + 0] = (v.x - m) * rs * gf.x + bf.x;
  lds[widx][lane * 4 + 1] = (v.y - m) * rs * gf.y + bf.y;
  lds[widx][lane * 4 + 2] = (v.z - m) * rs * gf.z + bf.z;
  lds[widx][lane * 4 + 3] = (v.w - m) * rs * gf.w + bf.w;
  __syncthreads();
  int vo = lane & 31, half = lane >> 5;
  const float* lp = &lds[widx][half * 128];
  const float* wp = wout + half * 128 * NVOCAB + vo;
  float acc = 0;
  #pragma unroll 4
  for (int d = 0; d < 128; ++d) acc += lp[d] * wp[d * NVOCAB];
  acc += __shfl_down(acc, 32, 64);
  if (lane < 32) out[bt * NVOCAB + vo] = acc + bout[vo];
}

extern "C" void kernel_launch(void* const* d_in, const int* in_sizes, int n_in,
                              void* d_out, int out_size, void* d_ws, size_t ws_size,
                              hipStream_t stream) {
  const int*   tokens = (const int*)d_in[0];
  const float* emb   = (const float*)d_in[1];
  const float* ffs   = (const float*)d_in[2];
  const float* ffb   = (const float*)d_in[3];
  const float* w1    = (const float*)d_in[4];
  const float* b1    = (const float*)d_in[5];
  const float* w2    = (const float*)d_in[6];
  const float* b2    = (const float*)d_in[7];
  const float* lnfs  = (const float*)d_in[8];
  const float* lnfb  = (const float*)d_in[9];
  const float* wout  = (const float*)d_in[10];
  const float* bout  = (const float*)d_in[11];
  float* out = (float*)d_out;

  char* ws = (char*)d_ws;
  float* x    = (float*)(ws);                         // 16 MB fp32
  u16*   y    = (u16*)  (ws + (size_t)16*1024*1024);  //  8 MB bf16 (residual stream)
  u16*   buf8 = (u16*)  (ws + (size_t)32*1024*1024);  //  8 MB bf16 (xv)
  u16*   qk   = (u16*)  (ws + (size_t)40*1024*1024);  //  8 MB bf16
  u16*   pln  = (u16*)  (ws + (size_t)48*1024*1024);  //  6 MB (12 planes)
  u16*   h    = (u16*)  (ws + (size_t)56*1024*1024);  // 32 MB bf16 (56..88)

  uint* cs = (uint*)(ws + (size_t)96*1024*1024);      // 96..100 (bigws)
  const int bigws = (ws_size >= (size_t)104*1024*1024) ? 1 : 0;
  if (!bigws){
    cs = (uint*)(ws + (size_t)48*1024*1024);           // 48..52 (pln unused then)
  }
  const int fuse = (ws_size >= (size_t)96*1024*1024) ? 1 : 0;
  u16* lnx = fuse ? (u16*)(ws + (size_t)88*1024*1024) : buf8; // bf16, 8 MB

  k_init<<<8192, 256, 0, stream>>>(tokens, emb, x, cs);
  if (bigws) k_splitall<<<1536, 256, 0, stream>>>(w1, w2, pln);
  for (int L = 0; L < NLAYER; ++L){
    k_rope<<<2048, 256, 0, stream>>>(x, cs, qk, buf8);
    k_attn2<<<256, 512, 0, stream>>>(qk, buf8, x, y,
                                     ffs + L*DD, ffb + L*DD, lnx, fuse);
    if (!fuse)
      k_ln<<<4096, 256, 0, stream>>>(y, ffs + L*DD, ffb + L*DD, lnx);
    const u16* PL;
    if (bigws){
      PL = pln + (size_t)L*2*PLN;
    } else {
      k_splitall<<<256, 256, 0, stream>>>(w1 + (size_t)L*PLN, w2 + (size_t)L*PLN, qk);
      PL = qk;
    }
    k_gemm<DD, HDIM, 0><<<2048, 256, 0, stream>>>(
        lnx, PL, b1 + L*HDIM, nullptr, nullptr, h);
    k_gemm<HDIM, DD, 1><<<512, 256, 0, stream>>>(
        h, PL + PLN, b2 + L*DD, y, x, nullptr);
  }
  k_final<<<4096, 256, 0, stream>>>(x, lnfs, lnfb, wout, bout, out);
}